// Round 5
// baseline (169.925 us; speedup 1.0000x reference)
//
#include <hip/hip_runtime.h>
#include <stdint.h>

// Exact k-subset sampler, 3-wave phase-specialized blocks.
// Block = 192 threads (3 waves) covering 64 rows (row r <-> lane r of each wave).
//   wave0: theta load -> up-pass (exact OCML expf/logf) -> tables to LDS;
//          after barrier: down-pass + marginals with native __expf/__logf
//          (marginals-only path; threshold 2e-2, never feeds argmax).
//   wave1/wave2: precompute root/li1/li2 gumbels (table-independent) before
//          the barrier; after barrier run the top-down count chain for sample
//          s = wave-1 using exact up-tables + exact OCML gumbels => samples
//          remain bit-identical to the reference (verified rounds 1-3 PRNG).
// LDS: per-lane column layout tab[entry*64 + lane] -> bank = lane%32, all
// accesses (uniform or divergent entry) are 2-way aliased = conflict-free.

__host__ __device__ __forceinline__ void tf2x32(uint32_t k0, uint32_t k1,
                                                uint32_t x0, uint32_t x1,
                                                uint32_t& y0, uint32_t& y1) {
  const uint32_t ks[3] = {k0, k1, k0 ^ k1 ^ 0x1BD11BDAu};
  x0 += ks[0]; x1 += ks[1];
  const int R0[4] = {13, 15, 26, 6};
  const int R1[4] = {17, 29, 16, 24};
#pragma unroll
  for (int i = 0; i < 5; ++i) {
    const int* R = (i & 1) ? R1 : R0;
#pragma unroll
    for (int r = 0; r < 4; ++r) {
      x0 += x1;
      x1 = (x1 << R[r]) | (x1 >> (32 - R[r]));
      x1 ^= x0;
    }
    x0 += ks[(i + 1) % 3];
    x1 += ks[(i + 2) % 3] + (uint32_t)(i + 1);
  }
  y0 = x0; y1 = x1;
}

struct TFKeys { uint32_t v[10]; };

// Exact gumbel (OCML logf) — must stay bit-identical to JAX reference.
__device__ __forceinline__ float gumbel_draw(uint32_t sk0, uint32_t sk1,
                                             uint32_t f) {
  uint32_t y0, y1;
  tf2x32(sk0, sk1, 0u, f, y0, y1);
  uint32_t bits = y0 ^ y1;
  uint32_t fb = (bits >> 9) | 0x3f800000u;
  float u = __uint_as_float(fb) - 1.0f;
  const float tiny = 1.17549435e-38f;
  float r = fmaxf(tiny, u + tiny);
  return -logf(-logf(r));
}

template<bool FAST> __device__ __forceinline__ float expT(float x) {
  return FAST ? __expf(x) : expf(x);
}
template<bool FAST> __device__ __forceinline__ float logT(float x) {
  return FAST ? __logf(x) : logf(x);
}

// o[m] = logsumexp_{j} aL[j] + aR[m-j] over in-support j, ascending-j sum.
template<int SIN, int SOUT, bool FAST>
__device__ __forceinline__ void conv_level(const float (&aL)[SIN],
                                           const float (&aR)[SIN],
                                           float (&o)[SOUT]) {
#pragma unroll
  for (int m = 1; m < SOUT; ++m) {
    const int jlo = (m - (SIN - 1) > 0) ? (m - (SIN - 1)) : 0;
    const int jhi = (m < SIN - 1) ? m : (SIN - 1);
    float t[SIN];
#pragma unroll
    for (int j = 0; j < SIN; ++j)
      if (j >= jlo && j <= jhi) t[j] = aL[j] + aR[m - j];
    float amax = t[jlo];
#pragma unroll
    for (int j = 0; j < SIN; ++j)
      if (j > jlo && j <= jhi) amax = fmaxf(amax, t[j]);
    float s = 0.0f;
#pragma unroll
    for (int j = 0; j < SIN; ++j)
      if (j >= jlo && j <= jhi) s += expT<FAST>(t[j] - amax);
    o[m] = logT<FAST>(s) + amax;
  }
}

// eo[m] = logsumexp_{j=max(0,m-SSIB+1)..m} ein[j] + sib[m-j]
template<int SSIB, int MLO, int MHI, bool FAST>
__device__ __forceinline__ void ext_level(const float (&ein)[8],
                                          const float* sib, float (&eo)[8]) {
#pragma unroll
  for (int m = MLO; m <= MHI; ++m) {
    const int jlo = (m - (SSIB - 1) > 0) ? (m - (SSIB - 1)) : 0;
    float t[8];
#pragma unroll
    for (int j = 0; j < 8; ++j)
      if (j >= jlo && j <= m) t[j] = ein[j] + sib[m - j];
    float amax = t[jlo];
#pragma unroll
    for (int j = 0; j < 8; ++j)
      if (j > jlo && j <= m) amax = fmaxf(amax, t[j]);
    float s = 0.0f;
#pragma unroll
    for (int j = 0; j < 8; ++j)
      if (j >= jlo && j <= m) s += expT<FAST>(t[j] - amax);
    eo[m] = logT<FAST>(s) + amax;
  }
}

// LDS entry map (all per-lane columns, stride 64):
//  th: 0..31 | L1m1: 32..47 | L1m2: 48..63 | L2: 64+n*4+(m-1) (n<8,m1..4)
//  L3: 96+n*8+(m-1) (n<4,m1..8) | L4: 128+n*8+(m-1) (n<2,m1..8)
#define NTAB 144

__global__ __launch_bounds__(192, 3) void simple_sampler_kernel(
    const float* __restrict__ scores, float* __restrict__ out,
    int nnodes, TFKeys keys) {
  const int tid = threadIdx.x;
  const int w = tid >> 6;
  const int lane = tid & 63;
  const int blk = blockIdx.x;
  const int row = blk * 64 + lane;
  const int node = row >> 3, e = row & 7;
  const int B = nnodes * 8;

  __shared__ float tab[NTAB * 64];
#define TAB(E) tab[(E) * 64 + lane]

  // wave0 register state (live across barrier)
  float th[32], l1[16], th2[16], l4[2][9];
  // sampling-wave pre-barrier gumbels
  float gr[9], g1v[18], g2v[20];
  uint32_t t9 = 0;

  if (w == 0) {
    const float* sc = scores + node * 256 + e;
#pragma unroll
    for (int c = 0; c < 32; ++c) th[c] = sc[c * 8];
#pragma unroll
    for (int c = 0; c < 32; ++c) TAB(c) = th[c];

    // ---- up pass (exact) ----
#pragma unroll
    for (int n4 = 0; n4 < 2; ++n4) {
      float l3h[2][8];
#pragma unroll
      for (int c3 = 0; c3 < 2; ++c3) {
        const int n3 = 2 * n4 + c3;
        float l2h[2][4];
#pragma unroll
        for (int c2 = 0; c2 < 2; ++c2) {
          const int n2 = 2 * n3 + c2;
#pragma unroll
          for (int c1 = 0; c1 < 2; ++c1) {
            const int n1 = 2 * n2 + c1;
            float tL = th[2 * n1], tR = th[2 * n1 + 1];
            float amax = fmaxf(tR, tL);            // t0=thR (j=0), t1=thL
            float s = expf(tR - amax) + expf(tL - amax);
            l1[n1] = logf(s) + amax;
            th2[n1] = tL + tR;                      // exact: log(1)+t = t
            TAB(32 + n1) = l1[n1];
            TAB(48 + n1) = th2[n1];
          }
          float aL[3] = {0.0f, l1[2 * n2], th2[2 * n2]};
          float aR[3] = {0.0f, l1[2 * n2 + 1], th2[2 * n2 + 1]};
          float o[5];
          conv_level<3, 5, false>(aL, aR, o);
#pragma unroll
          for (int m = 1; m < 5; ++m) {
            l2h[c2][m - 1] = o[m];
            TAB(64 + n2 * 4 + m - 1) = o[m];
          }
        }
        float aL[5], aR[5];
        aL[0] = 0.0f; aR[0] = 0.0f;
#pragma unroll
        for (int m = 1; m < 5; ++m) { aL[m] = l2h[0][m - 1]; aR[m] = l2h[1][m - 1]; }
        float o[9];
        conv_level<5, 9, false>(aL, aR, o);
#pragma unroll
        for (int m = 1; m < 9; ++m) {
          l3h[c3][m - 1] = o[m];
          TAB(96 + n3 * 8 + m - 1) = o[m];
        }
      }
      float aL[9], aR[9];
      aL[0] = 0.0f; aR[0] = 0.0f;
#pragma unroll
      for (int m = 1; m < 9; ++m) { aL[m] = l3h[0][m - 1]; aR[m] = l3h[1][m - 1]; }
      float o[9];
      conv_level<9, 9, false>(aL, aR, o);
      l4[n4][0] = 0.0f;
#pragma unroll
      for (int m = 1; m < 9; ++m) {
        l4[n4][m] = o[m];
        TAB(128 + n4 * 8 + m - 1) = o[m];
      }
    }
  } else {
    // ---- sampling waves: pre-barrier gumbel production (table-independent)
    const int s = w - 1;
    t9 = ((uint32_t)s * (uint32_t)B + (uint32_t)row) * 9u;
#pragma unroll
    for (int j = 0; j < 9; ++j)
      gr[j] = gumbel_draw(keys.v[0], keys.v[1], t9 + (uint32_t)j);
#pragma unroll
    for (int i = 0; i < 2; ++i)
#pragma unroll
      for (int j = 0; j < 9; ++j)
        g1v[i * 9 + j] = gumbel_draw(keys.v[2], keys.v[3],
                                     2u * t9 + (uint32_t)(i * 9 + j));
#pragma unroll
    for (int i = 0; i < 4; ++i)
#pragma unroll
      for (int j = 0; j < 5; ++j)
        g2v[i * 5 + j] = gumbel_draw(keys.v[4], keys.v[5],
                                     4u * t9 + (uint32_t)(i * 9 + j));
  }

  __syncthreads();

  if (w == 0) {
    // ---- logZ (feeds marginals only -> fast) ----
    float logZ;
    {
      float t[9];
#pragma unroll
      for (int j = 0; j < 9; ++j) t[j] = l4[0][j] + l4[1][8 - j];
      float amax = t[0];
#pragma unroll
      for (int j = 1; j < 9; ++j) amax = fmaxf(amax, t[j]);
      float s = 0.0f;
#pragma unroll
      for (int j = 0; j < 9; ++j) s += __expf(t[j] - amax);
      logZ = __logf(s) + amax;
    }
    // ---- down pass (marginals only -> fast transcendentals) ----
    float e4[2][8];
#pragma unroll
    for (int n = 0; n < 2; ++n) {
      e4[n][0] = 0.0f;
#pragma unroll
      for (int m = 1; m < 8; ++m) e4[n][m] = l4[1 - n][m];
    }
    float* mb = out + 2 * B * 32 + node * 256 + e;
#pragma unroll
    for (int n3 = 0; n3 < 4; ++n3) {
      float sib3[9];
      sib3[0] = 0.0f; sib3[8] = 0.0f;
#pragma unroll
      for (int m = 1; m < 8; ++m) sib3[m] = TAB(96 + (n3 ^ 1) * 8 + m - 1);
      float e3[8];
      ext_level<9, 0, 7, true>(e4[n3 >> 1], sib3, e3);
#pragma unroll
      for (int c2 = 0; c2 < 2; ++c2) {
        const int n2 = 2 * n3 + c2;
        float sib2[5];
        sib2[0] = 0.0f;
#pragma unroll
        for (int m = 1; m < 5; ++m) sib2[m] = TAB(64 + (n2 ^ 1) * 4 + m - 1);
        float e2[8];
        ext_level<5, 4, 7, true>(e3, sib2, e2);
#pragma unroll
        for (int c1 = 0; c1 < 2; ++c1) {
          const int n1 = 2 * n2 + c1;
          float sib1[3] = {0.0f, l1[n1 ^ 1], th2[n1 ^ 1]};
          float e1m[8];
          ext_level<3, 6, 7, true>(e2, sib1, e1m);
          {
            float t6 = e1m[6] + th[2 * n1 + 1];
            float t7 = e1m[7] + 0.0f;
            float amax = fmaxf(t6, t7);
            float s = __expf(t6 - amax) + __expf(t7 - amax);
            float ext7 = __logf(s) + amax;
            mb[(2 * n1) * 8] = __expf((th[2 * n1] + ext7) - logZ);
          }
          {
            float t6 = e1m[6] + th[2 * n1];
            float t7 = e1m[7] + 0.0f;
            float amax = fmaxf(t6, t7);
            float s = __expf(t6 - amax) + __expf(t7 - amax);
            float ext7 = __logf(s) + amax;
            mb[(2 * n1 + 1) * 8] = __expf((th[2 * n1 + 1] + ext7) - logZ);
          }
        }
      }
    }
  } else {
    // ---- top-down count chain, sample s = w-1 (bit-exact path) ----
    const int s = w - 1;
    // root (L4 tables), c = 8
    uint32_t pk;
    {
      float a4a[9], a4b[9];
      a4a[0] = 0.0f; a4b[0] = 0.0f;
#pragma unroll
      for (int m = 1; m < 9; ++m) {
        a4a[m] = TAB(128 + m - 1);
        a4b[m] = TAB(136 + m - 1);
      }
      float best = a4a[0] + a4b[8] + gr[0];
      int bj = 0;
#pragma unroll
      for (int j = 1; j < 9; ++j) {
        float v = (a4a[j] + a4b[8 - j]) + gr[j];
        if (v > best) { best = v; bj = j; }
      }
      pk = (uint32_t)bj | ((uint32_t)(8 - bj) << 4);
    }
    // li=1: 2 tasks, J=9, L3 tables
    {
      uint32_t npk = 0;
#pragma unroll
      for (int i = 0; i < 2; ++i) {
        int c = (int)((pk >> (4 * i)) & 15u);
        float aLr[9];
        aLr[0] = 0.0f;
#pragma unroll
        for (int m = 1; m < 9; ++m) aLr[m] = TAB(96 + 16 * i + m - 1);
        float best = -3.0e38f; int bj = 0;
#pragma unroll
        for (int j = 0; j < 9; ++j) {
          int idx = c - j;
          int cl = min(max(idx, 1), 8);
          float ar = tab[(96 + 16 * i + 8 + cl - 1) * 64 + lane];
          float af = (idx == 0) ? 0.0f : ar;
          float v = (aLr[j] + af) + g1v[9 * i + j];
          if (idx >= 0 && v > best) { best = v; bj = j; }
        }
        npk |= ((uint32_t)bj << (8 * i)) | ((uint32_t)(c - bj) << (8 * i + 4));
      }
      pk = npk;
    }
    // li=2: 4 tasks, J=5, L2 tables
    {
      uint32_t npk = 0;
#pragma unroll
      for (int i = 0; i < 4; ++i) {
        int c = (int)((pk >> (4 * i)) & 15u);
        float aLr[5];
        aLr[0] = 0.0f;
#pragma unroll
        for (int m = 1; m < 5; ++m) aLr[m] = TAB(64 + 8 * i + m - 1);
        float best = -3.0e38f; int bj = 0;
#pragma unroll
        for (int j = 0; j < 5; ++j) {
          int idx = c - j;
          int cl = min(max(idx, 1), 4);
          float ar = tab[(64 + 8 * i + 4 + cl - 1) * 64 + lane];
          float af = (idx == 0) ? 0.0f : ar;
          float v = (aLr[j] + af) + g2v[5 * i + j];
          if (idx >= 0 && idx <= 4 && v > best) { best = v; bj = j; }
        }
        npk |= ((uint32_t)bj << (8 * i)) | ((uint32_t)(c - bj) << (8 * i + 4));
      }
      pk = npk;
    }
    // li=3: 8 tasks, J=3, L1 tables (runtime loop, inline draws)
    uint64_t pk64 = 0;
    {
      const uint32_t sk0 = keys.v[6], sk1 = keys.v[7];
      const uint32_t fb0 = 8u * t9;
#pragma unroll 1
      for (int i = 0; i < 8; ++i) {
        int c = (int)((pk >> (4 * i)) & 15u);
        float aL1 = TAB(32 + 2 * i);
        float aL2 = TAB(48 + 2 * i);
        uint32_t fb = fb0 + (uint32_t)(i * 9);
        float best = -3.0e38f; int bj = 0;
#pragma unroll
        for (int j = 0; j < 3; ++j) {
          float g = gumbel_draw(sk0, sk1, fb + (uint32_t)j);
          int idx = c - j;
          int cl = min(max(idx, 1), 2);
          float ar = tab[(32 + (cl - 1) * 16 + 2 * i + 1) * 64 + lane];
          float af = (idx == 0) ? 0.0f : ar;
          float aLj = (j == 0) ? 0.0f : ((j == 1) ? aL1 : aL2);
          float v = (aLj + af) + g;
          if (idx >= 0 && idx <= 2 && v > best) { best = v; bj = j; }
        }
        pk64 |= ((uint64_t)(uint32_t)bj << (8 * i)) |
                ((uint64_t)(uint32_t)(c - bj) << (8 * i + 4));
      }
    }
    // li=4: 16 leaf tasks, J=2 (runtime loop, th from LDS)
    {
      const uint32_t sk0 = keys.v[8], sk1 = keys.v[9];
      const uint32_t fb0 = 16u * t9;
      float* bs = out + s * (B * 32) + node * 256 + e;
#pragma unroll 1
      for (int i = 0; i < 16; ++i) {
        int c = (int)((uint32_t)(pk64 >> (4 * i)) & 15u);
        float thL = TAB(2 * i);
        float thR = TAB(2 * i + 1);
        uint32_t fb = fb0 + (uint32_t)(i * 9);
        float g0 = gumbel_draw(sk0, sk1, fb);
        float g1 = gumbel_draw(sk0, sk1, fb + 1u);
        float best = -3.0e38f; int bj = 0;
        bool v0ok = (c <= 1);
        if (v0ok) { best = ((c == 0) ? 0.0f : thR) + g0; bj = 0; }
        int idx = c - 1;
        if (idx >= 0) {
          float v1 = (thL + ((idx == 0) ? 0.0f : thR)) + g1;
          if (v1 > best) { bj = 1; }
        }
        bs[16 * i] = (float)bj;
        bs[16 * i + 8] = (float)(c - bj);
      }
    }
  }
}

extern "C" void kernel_launch(void* const* d_in, const int* in_sizes, int n_in,
                              void* d_out, int out_size, void* d_ws, size_t ws_size,
                              hipStream_t stream) {
  const float* scores = (const float*)d_in[0];
  float* out = (float*)d_out;
  const int nnodes = in_sizes[0] / (32 * 8);   // 8192
  const int B = nnodes * 8;                    // 65536 rows

  // key = jax.random.key(42); per level: key, sub = split(key)
  // (partitionable threefry: new = tf(key,(0,0)), sub = tf(key,(0,1)))
  TFKeys K;
  uint32_t k0 = 0u, k1 = 42u;
  for (int t = 0; t < 5; ++t) {
    uint32_t n0, n1, s0, s1;
    tf2x32(k0, k1, 0u, 0u, n0, n1);
    tf2x32(k0, k1, 0u, 1u, s0, s1);
    K.v[2 * t] = s0; K.v[2 * t + 1] = s1;
    k0 = n0; k1 = n1;
  }

  dim3 grid((unsigned)(B / 64)), block(192);
  hipLaunchKernelGGL(simple_sampler_kernel, grid, block, 0, stream,
                     scores, out, nnodes, K);
}

// Round 6
// 136.655 us; speedup vs baseline: 1.2435x; 1.2435x over previous
//
#include <hip/hip_runtime.h>
#include <stdint.h>

// Exact k-subset sampler, pair-per-row data-parallel layout, ZERO barriers.
// Wave = 32 rows x 2 lanes (r = lane>>1, p = lane&1). Both pair lanes:
//   - load theta, run the exact up-pass in registers (duplicated),
//   - run the fast-path down-pass + marginals (duplicated; threshold 2e-2),
//     each lane storing the parity-p marginal outputs,
//   - run the top-down Gumbel chain for sample s = p (bit-exact: exact OCML
//     up-tables + exact OCML gumbel logf, ascending-j first-max argmax).
// Runtime-indexed table reads come from wave-private LDS (in-order DS within
// a wave -> no __syncthreads anywhere). All pruning removes only exact-0.0f
// logsumexp terms / never-read entries (verified bit-exact rounds 1-3,5).

__host__ __device__ __forceinline__ void tf2x32(uint32_t k0, uint32_t k1,
                                                uint32_t x0, uint32_t x1,
                                                uint32_t& y0, uint32_t& y1) {
  const uint32_t ks[3] = {k0, k1, k0 ^ k1 ^ 0x1BD11BDAu};
  x0 += ks[0]; x1 += ks[1];
  const int R0[4] = {13, 15, 26, 6};
  const int R1[4] = {17, 29, 16, 24};
#pragma unroll
  for (int i = 0; i < 5; ++i) {
    const int* R = (i & 1) ? R1 : R0;
#pragma unroll
    for (int rr = 0; rr < 4; ++rr) {
      x0 += x1;
      x1 = (x1 << R[rr]) | (x1 >> (32 - R[rr]));
      x1 ^= x0;
    }
    x0 += ks[(i + 1) % 3];
    x1 += ks[(i + 2) % 3] + (uint32_t)(i + 1);
  }
  y0 = x0; y1 = x1;
}

struct TFKeys { uint32_t v[10]; };

// Exact gumbel (OCML logf) — must stay bit-identical to JAX reference.
__device__ __forceinline__ float gumbel_draw(uint32_t sk0, uint32_t sk1,
                                             uint32_t f) {
  uint32_t y0, y1;
  tf2x32(sk0, sk1, 0u, f, y0, y1);
  uint32_t bits = y0 ^ y1;
  uint32_t fb = (bits >> 9) | 0x3f800000u;
  float u = __uint_as_float(fb) - 1.0f;
  const float tiny = 1.17549435e-38f;
  float rr = fmaxf(tiny, u + tiny);
  return -logf(-logf(rr));
}

template<bool FAST> __device__ __forceinline__ float expT(float x) {
  return FAST ? __expf(x) : expf(x);
}
template<bool FAST> __device__ __forceinline__ float logT(float x) {
  return FAST ? __logf(x) : logf(x);
}

// o[m] = logsumexp_j aL[j] + aR[m-j] over in-support j, ascending-j sum.
template<int SIN, int SOUT, bool FAST>
__device__ __forceinline__ void conv_level(const float (&aL)[SIN],
                                           const float (&aR)[SIN],
                                           float (&o)[SOUT]) {
#pragma unroll
  for (int m = 1; m < SOUT; ++m) {
    const int jlo = (m - (SIN - 1) > 0) ? (m - (SIN - 1)) : 0;
    const int jhi = (m < SIN - 1) ? m : (SIN - 1);
    float t[SIN];
#pragma unroll
    for (int j = 0; j < SIN; ++j)
      if (j >= jlo && j <= jhi) t[j] = aL[j] + aR[m - j];
    float amax = t[jlo];
#pragma unroll
    for (int j = 0; j < SIN; ++j)
      if (j > jlo && j <= jhi) amax = fmaxf(amax, t[j]);
    float s = 0.0f;
#pragma unroll
    for (int j = 0; j < SIN; ++j)
      if (j >= jlo && j <= jhi) s += expT<FAST>(t[j] - amax);
    o[m] = logT<FAST>(s) + amax;
  }
}

// eo[m] = logsumexp_{j=max(0,m-SSIB+1)..m} ein[j] + sib[m-j]
template<int SSIB, int MLO, int MHI, bool FAST>
__device__ __forceinline__ void ext_level(const float (&ein)[8],
                                          const float* sib, float (&eo)[8]) {
#pragma unroll
  for (int m = MLO; m <= MHI; ++m) {
    const int jlo = (m - (SSIB - 1) > 0) ? (m - (SSIB - 1)) : 0;
    float t[8];
#pragma unroll
    for (int j = 0; j < 8; ++j)
      if (j >= jlo && j <= m) t[j] = ein[j] + sib[m - j];
    float amax = t[jlo];
#pragma unroll
    for (int j = 0; j < 8; ++j)
      if (j > jlo && j <= m) amax = fmaxf(amax, t[j]);
    float s = 0.0f;
#pragma unroll
    for (int j = 0; j < 8; ++j)
      if (j >= jlo && j <= m) s += expT<FAST>(t[j] - amax);
    eo[m] = logT<FAST>(s) + amax;
  }
}

// Per-row LDS entry map (stride 32 over r):
//  L3 odd node o (o=0,1), m=1..8   : o*8 + (m-1)        ->  0..15
//  L2 odd node o (o=0..3), m=1..4  : 16 + o*4 + (m-1)   -> 16..31
//  L1 odd node o (o=0..7), m=1     : 32 + o             -> 32..39
//  L1 odd node o,          m=2     : 40 + o             -> 40..47
//  L1 even node i,         m=1     : 48 + i             -> 48..55
//  L1 even node i,         m=2     : 56 + i             -> 56..63
//  theta c (0..31)                 : 64 + c             -> 64..95
#define ENT 96

__global__ __launch_bounds__(256, 2) void simple_sampler_kernel(
    const float* __restrict__ scores, float* __restrict__ out,
    int nnodes, TFKeys keys) {
  const int tid = threadIdx.x;
  const int w = tid >> 6;
  const int lane = tid & 63;
  const int p = lane & 1;        // sample id for this lane
  const int r = lane >> 1;       // row-local 0..31
  const int row = (blockIdx.x * 4 + w) * 32 + r;
  const int node = row >> 3, e = row & 7;
  const int B = nnodes * 8;

  __shared__ float lds[4 * ENT * 32];
  float* W = &lds[w * (ENT * 32)];
#define L(E) W[(E) * 32 + r]

  // ---- load theta (pair-duplicated; L1/L2 serve the dup) ----
  float th[32];
  const float* sc = scores + node * 256 + e;
#pragma unroll
  for (int c = 0; c < 32; ++c) th[c] = sc[c * 8];
#pragma unroll
  for (int c = 0; c < 32; ++c) L(64 + c) = th[c];

  // ---- up pass (exact OCML, registers; odd tables also to LDS) ----
  float l1e[8], th2e[8], l2e[4][4], l3e[2][8], l4[2][9];
#pragma unroll
  for (int n4 = 0; n4 < 2; ++n4) {
    float l3t[2][9];
#pragma unroll
    for (int c3 = 0; c3 < 2; ++c3) {
      const int n3 = 2 * n4 + c3;
      float l2t[2][5];
#pragma unroll
      for (int c2 = 0; c2 < 2; ++c2) {
        const int n2 = 2 * n3 + c2;
        float m1v[2], m2v[2];
#pragma unroll
        for (int c1 = 0; c1 < 2; ++c1) {
          const int n1 = 2 * n2 + c1;
          float tL = th[2 * n1], tR = th[2 * n1 + 1];
          float amax = fmaxf(tR, tL);            // t0 = thR (j=0), t1 = thL
          float s = expf(tR - amax) + expf(tL - amax);
          m1v[c1] = logf(s) + amax;
          m2v[c1] = tL + tR;                      // exact: logf(1.0f)==0.0f
        }
        l1e[n2] = m1v[0]; th2e[n2] = m2v[0];
        L(48 + n2) = m1v[0]; L(56 + n2) = m2v[0];
        L(32 + n2) = m1v[1]; L(40 + n2) = m2v[1];
        float aL[3] = {0.0f, m1v[0], m2v[0]};
        float aR[3] = {0.0f, m1v[1], m2v[1]};
        float o5[5];
        conv_level<3, 5, false>(aL, aR, o5);
        l2t[c2][0] = 0.0f;
#pragma unroll
        for (int m = 1; m < 5; ++m) {
          l2t[c2][m] = o5[m];
          if (c2 == 0) l2e[n3][m - 1] = o5[m];
          else         L(16 + n3 * 4 + m - 1) = o5[m];
        }
      }
      float o9[9];
      conv_level<5, 9, false>(l2t[0], l2t[1], o9);
      l3t[c3][0] = 0.0f;
#pragma unroll
      for (int m = 1; m < 9; ++m) {
        l3t[c3][m] = o9[m];
        if (c3 == 0) l3e[n4][m - 1] = o9[m];
        else         L(n4 * 8 + m - 1) = o9[m];
      }
    }
    float o9[9];
    conv_level<9, 9, false>(l3t[0], l3t[1], o9);
    l4[n4][0] = 0.0f;
#pragma unroll
    for (int m = 1; m < 9; ++m) l4[n4][m] = o9[m];
  }

  // ---- logZ (marginals only -> fast) ----
  float logZ;
  {
    float t[9];
#pragma unroll
    for (int j = 0; j < 9; ++j) t[j] = l4[0][j] + l4[1][8 - j];
    float amax = t[0];
#pragma unroll
    for (int j = 1; j < 9; ++j) amax = fmaxf(amax, t[j]);
    float s = 0.0f;
#pragma unroll
    for (int j = 0; j < 9; ++j) s += __expf(t[j] - amax);
    logZ = __logf(s) + amax;
  }

  // ---- down pass + marginals (fast path; duplicated on pair, each lane
  //      stores the parity-p outputs) ----
  {
    float e4[2][8];
#pragma unroll
    for (int n = 0; n < 2; ++n) {
      e4[n][0] = 0.0f;
#pragma unroll
      for (int m = 1; m < 8; ++m) e4[n][m] = l4[1 - n][m];
    }
    float* mb = out + 2 * B * 32 + node * 256 + e;
#pragma unroll
    for (int n3 = 0; n3 < 4; ++n3) {
      float sib3[8];
      sib3[0] = 0.0f;
#pragma unroll
      for (int m = 1; m < 8; ++m)
        sib3[m] = (n3 & 1) ? l3e[n3 >> 1][m - 1] : L((n3 >> 1) * 8 + m - 1);
      float e3[8];
      ext_level<9, 0, 7, true>(e4[n3 >> 1], sib3, e3);
#pragma unroll
      for (int c2 = 0; c2 < 2; ++c2) {
        const int n2 = 2 * n3 + c2;
        float sib2[5];
        sib2[0] = 0.0f;
#pragma unroll
        for (int m = 1; m < 5; ++m)
          sib2[m] = (n2 & 1) ? l2e[n2 >> 1][m - 1]
                             : L(16 + (n2 >> 1) * 4 + m - 1);
        float e2v[8];
        ext_level<5, 4, 7, true>(e3, sib2, e2v);
#pragma unroll
        for (int c1 = 0; c1 < 2; ++c1) {
          const int n1 = 2 * n2 + c1;
          float s1m1 = (n1 & 1) ? l1e[n1 >> 1] : L(32 + (n1 >> 1));
          float s1m2 = (n1 & 1) ? th2e[n1 >> 1] : L(40 + (n1 >> 1));
          float sib1[3] = {0.0f, s1m1, s1m2};
          float e1m[8];
          ext_level<3, 6, 7, true>(e2v, sib1, e1m);
          float mA, mB;
          {
            float t6 = e1m[6] + th[2 * n1 + 1];
            float t7 = e1m[7];
            float amax = fmaxf(t6, t7);
            float s = __expf(t6 - amax) + __expf(t7 - amax);
            mA = __expf((th[2 * n1] + (__logf(s) + amax)) - logZ);
          }
          {
            float t6 = e1m[6] + th[2 * n1];
            float t7 = e1m[7];
            float amax = fmaxf(t6, t7);
            float s = __expf(t6 - amax) + __expf(t7 - amax);
            mB = __expf((th[2 * n1 + 1] + (__logf(s) + amax)) - logZ);
          }
          mb[(2 * n1 + p) * 8] = p ? mB : mA;
        }
      }
    }
  }

  // ---- top-down sampling, sample s = p (bit-exact path) ----
  const uint32_t t9 = (uint32_t)(p * B + row) * 9u;
  int cLr, cRr;
  {  // root, c = 8, all-static tables
    float best = 0.0f; int bj = 0;
#pragma unroll
    for (int j = 0; j < 9; ++j) {
      float g = gumbel_draw(keys.v[0], keys.v[1], t9 + (uint32_t)j);
      float v = (l4[0][j] + l4[1][8 - j]) + g;
      if (j == 0) { best = v; } else if (v > best) { best = v; bj = j; }
    }
    cLr = bj; cRr = 8 - bj;
  }
  int c1v[4];
  {  // li=1: 2 tasks, J=9, aL = L3 even (regs), aR = L3 odd (LDS)
#pragma unroll
    for (int i = 0; i < 2; ++i) {
      int c = (i == 0) ? cLr : cRr;
      float best = -3.0e38f; int bj = 0;
#pragma unroll
      for (int j = 0; j < 9; ++j) {
        float g = gumbel_draw(keys.v[2], keys.v[3],
                              2u * t9 + (uint32_t)(i * 9 + j));
        int idx = c - j;
        int cl = min(max(idx, 1), 8);
        float ar = L(i * 8 + cl - 1);
        float af = (idx == 0) ? 0.0f : ar;
        float aLj = (j == 0) ? 0.0f : l3e[i][j - 1];
        float v = (aLj + af) + g;
        if (idx >= 0 && v > best) { best = v; bj = j; }
      }
      c1v[2 * i] = bj; c1v[2 * i + 1] = c - bj;
    }
  }
  uint32_t pk2 = 0;
  {  // li=2: 4 tasks, J=5
#pragma unroll
    for (int i = 0; i < 4; ++i) {
      int c = c1v[i];
      float best = -3.0e38f; int bj = 0;
#pragma unroll
      for (int j = 0; j < 5; ++j) {
        float g = gumbel_draw(keys.v[4], keys.v[5],
                              4u * t9 + (uint32_t)(i * 9 + j));
        int idx = c - j;
        int cl = min(max(idx, 1), 4);
        float ar = L(16 + i * 4 + cl - 1);
        float af = (idx == 0) ? 0.0f : ar;
        float aLj = (j == 0) ? 0.0f : l2e[i][j - 1];
        float v = (aLj + af) + g;
        if (idx >= 0 && idx <= 4 && v > best) { best = v; bj = j; }
      }
      pk2 |= ((uint32_t)bj << (8 * i)) | ((uint32_t)(c - bj) << (8 * i + 4));
    }
  }
  uint64_t pk64 = 0;
  {  // li=3: 8 tasks, J=3 (all tables from LDS -> rolled loop ok)
    const uint32_t sk0 = keys.v[6], sk1 = keys.v[7];
    const uint32_t fb0 = 8u * t9;
#pragma unroll 2
    for (int i = 0; i < 8; ++i) {
      int c = (int)((pk2 >> (4 * i)) & 15u);
      float aL1 = L(48 + i), aL2 = L(56 + i);
      float arm1 = L(32 + i), arm2 = L(40 + i);
      uint32_t fb = fb0 + (uint32_t)(i * 9);
      float best = -3.0e38f; int bj = 0;
#pragma unroll
      for (int j = 0; j < 3; ++j) {
        float g = gumbel_draw(sk0, sk1, fb + (uint32_t)j);
        int idx = c - j;
        float af = (idx == 1) ? arm1 : ((idx == 2) ? arm2 : 0.0f);
        float aLj = (j == 0) ? 0.0f : ((j == 1) ? aL1 : aL2);
        float v = (aLj + af) + g;
        if (idx >= 0 && idx <= 2 && v > best) { best = v; bj = j; }
      }
      pk64 |= ((uint64_t)(uint32_t)bj << (8 * i)) |
              ((uint64_t)(uint32_t)(c - bj) << (8 * i + 4));
    }
  }
  {  // li=4: 16 leaf tasks, J=2; stores
    const uint32_t sk0 = keys.v[8], sk1 = keys.v[9];
    const uint32_t fb0 = 16u * t9;
    float* bs = out + p * (B * 32) + node * 256 + e;
#pragma unroll 2
    for (int i = 0; i < 16; ++i) {
      int c = (int)((uint32_t)(pk64 >> (4 * i)) & 15u);
      float thL = L(64 + 2 * i);
      float thR = L(64 + 2 * i + 1);
      uint32_t fb = fb0 + (uint32_t)(i * 9);
      float g0 = gumbel_draw(sk0, sk1, fb);
      float g1 = gumbel_draw(sk0, sk1, fb + 1u);
      float best = -3.0e38f; int bj = 0;
      if (c <= 1) { best = ((c == 0) ? 0.0f : thR) + g0; bj = 0; }
      int idx = c - 1;
      if (idx >= 0) {
        float v1 = (thL + ((idx == 0) ? 0.0f : thR)) + g1;
        if (v1 > best) { bj = 1; }
      }
      bs[16 * i] = (float)bj;
      bs[16 * i + 8] = (float)(c - bj);
    }
  }
#undef L
}

extern "C" void kernel_launch(void* const* d_in, const int* in_sizes, int n_in,
                              void* d_out, int out_size, void* d_ws, size_t ws_size,
                              hipStream_t stream) {
  const float* scores = (const float*)d_in[0];
  float* out = (float*)d_out;
  const int nnodes = in_sizes[0] / (32 * 8);   // 8192
  const int B = nnodes * 8;                    // 65536 rows

  // key = jax.random.key(42); per level: key, sub = split(key)
  // (partitionable threefry: new = tf(key,(0,0)), sub = tf(key,(0,1)))
  TFKeys K;
  uint32_t k0 = 0u, k1 = 42u;
  for (int t = 0; t < 5; ++t) {
    uint32_t n0, n1, s0, s1;
    tf2x32(k0, k1, 0u, 0u, n0, n1);
    tf2x32(k0, k1, 0u, 1u, s0, s1);
    K.v[2 * t] = s0; K.v[2 * t + 1] = s1;
    k0 = n0; k1 = n1;
  }

  dim3 grid((unsigned)(B / 128)), block(256);
  hipLaunchKernelGGL(simple_sampler_kernel, grid, block, 0, stream,
                     scores, out, nnodes, K);
}

// Round 7
// 113.976 us; speedup vs baseline: 1.4909x; 1.1990x over previous
//
#include <hip/hip_runtime.h>
#include <stdint.h>

// Exact k-subset sampler, pair-per-row layout, zero __syncthreads.
// Wave = 32 rows x 2 lanes (r = lane>>1, p = lane&1).
//   - up-pass SPLIT: lane p computes subtree n4=p (exact OCML expf/logf),
//     writes its half's tables to LDS; halves exchanged via in-wave LDS
//     ordering (wave_barrier stops compiler reordering; HW DS is in-order).
//   - down-pass SPLIT: lane p computes ext for n3 in {2p,2p+1} (fast
//     __expf/__logf path; marginals only, threshold 2e-2) and stores the 16
//     marginal columns of its subtree.
//   - sampling: lane p runs sample p's top-down chain (bit-exact: exact
//     up-tables + exact OCML gumbels, ascending-j first-max). li1 uses a
//     compacted <=10-draw loop (feasible j only; singletons skip draws);
//     li4 draws only for count==1 leaf pairs (others are argmax-of-one).
//     All skipped draws are infeasible (-1e10 + g never wins) or unused =>
//     bitwise-identical samples (PRNG verified rounds 1-6).

__host__ __device__ __forceinline__ void tf2x32(uint32_t k0, uint32_t k1,
                                                uint32_t x0, uint32_t x1,
                                                uint32_t& y0, uint32_t& y1) {
  const uint32_t ks[3] = {k0, k1, k0 ^ k1 ^ 0x1BD11BDAu};
  x0 += ks[0]; x1 += ks[1];
  const int R0[4] = {13, 15, 26, 6};
  const int R1[4] = {17, 29, 16, 24};
#pragma unroll
  for (int i = 0; i < 5; ++i) {
    const int* R = (i & 1) ? R1 : R0;
#pragma unroll
    for (int rr = 0; rr < 4; ++rr) {
      x0 += x1;
      x1 = (x1 << R[rr]) | (x1 >> (32 - R[rr]));
      x1 ^= x0;
    }
    x0 += ks[(i + 1) % 3];
    x1 += ks[(i + 2) % 3] + (uint32_t)(i + 1);
  }
  y0 = x0; y1 = x1;
}

struct TFKeys { uint32_t v[10]; };

// Exact gumbel (OCML logf) — must stay bit-identical to JAX reference.
__device__ __forceinline__ float gumbel_draw(uint32_t sk0, uint32_t sk1,
                                             uint32_t f) {
  uint32_t y0, y1;
  tf2x32(sk0, sk1, 0u, f, y0, y1);
  uint32_t bits = y0 ^ y1;
  uint32_t fb = (bits >> 9) | 0x3f800000u;
  float u = __uint_as_float(fb) - 1.0f;
  const float tiny = 1.17549435e-38f;
  float rr = fmaxf(tiny, u + tiny);
  return -logf(-logf(rr));
}

template<bool FAST> __device__ __forceinline__ float expT(float x) {
  return FAST ? __expf(x) : expf(x);
}
template<bool FAST> __device__ __forceinline__ float logT(float x) {
  return FAST ? __logf(x) : logf(x);
}

// o[m] = logsumexp_j aL[j] + aR[m-j] over in-support j, ascending-j sum.
// aL/aR value arrays with [0] == 0.0f.
template<int SIN, int SOUT, bool FAST>
__device__ __forceinline__ void conv_level(const float (&aL)[SIN],
                                           const float (&aR)[SIN],
                                           float (&o)[SOUT]) {
#pragma unroll
  for (int m = 1; m < SOUT; ++m) {
    const int jlo = (m - (SIN - 1) > 0) ? (m - (SIN - 1)) : 0;
    const int jhi = (m < SIN - 1) ? m : (SIN - 1);
    float t[SIN];
#pragma unroll
    for (int j = 0; j < SIN; ++j)
      if (j >= jlo && j <= jhi) t[j] = aL[j] + aR[m - j];
    float amax = t[jlo];
#pragma unroll
    for (int j = 0; j < SIN; ++j)
      if (j > jlo && j <= jhi) amax = fmaxf(amax, t[j]);
    float s = 0.0f;
#pragma unroll
    for (int j = 0; j < SIN; ++j)
      if (j >= jlo && j <= jhi) s += expT<FAST>(t[j] - amax);
    o[m] = logT<FAST>(s) + amax;
  }
}

// eo[m] = logsumexp_{j=max(0,m-SSIB+1)..m} ein[j] + sib[m-j]
template<int SSIB, int MLO, int MHI, bool FAST>
__device__ __forceinline__ void ext_level(const float (&ein)[8],
                                          const float* sib, float (&eo)[8]) {
#pragma unroll
  for (int m = MLO; m <= MHI; ++m) {
    const int jlo = (m - (SSIB - 1) > 0) ? (m - (SSIB - 1)) : 0;
    float t[8];
#pragma unroll
    for (int j = 0; j < 8; ++j)
      if (j >= jlo && j <= m) t[j] = ein[j] + sib[m - j];
    float amax = t[jlo];
#pragma unroll
    for (int j = 0; j < 8; ++j)
      if (j > jlo && j <= m) amax = fmaxf(amax, t[j]);
    float s = 0.0f;
#pragma unroll
    for (int j = 0; j < 8; ++j)
      if (j >= jlo && j <= m) s += expT<FAST>(t[j] - amax);
    eo[m] = logT<FAST>(s) + amax;
  }
}

// Per-row LDS entry map (stride 32 over r; bank = r%32 for ALL entries ->
// worst 2-way alias across the pair = free):
//  theta col c        : 0..31
//  L1 m=1, node n1    : 32 + n1   (n1 0..15)
//  L1 m=2, node n1    : 48 + n1
//  L2 node n2, m=1..4 : 64 + n2*4 + (m-1)   (n2 0..7)
//  L3 node n3, m=1..8 : 96 + n3*8 + (m-1)   (n3 0..3)
//  L4 node n4, m=1..8 : 128 + n4*8 + (m-1)  (n4 0..1)
#define ENT 144

__global__ __launch_bounds__(128, 2) void simple_sampler_kernel(
    const float* __restrict__ scores, float* __restrict__ out,
    int nnodes, TFKeys keys) {
  const int tid = threadIdx.x;
  const int w = tid >> 6;
  const int lane = tid & 63;
  const int p = lane & 1;        // sample id / subtree id for this lane
  const int r = lane >> 1;       // row-local 0..31
  const int row = (blockIdx.x * 2 + w) * 32 + r;
  const int node = row >> 3, e = row & 7;
  const int B = nnodes * 8;

  __shared__ float lds[2 * ENT * 32];
  float* W = &lds[w * (ENT * 32)];
#define L(E) W[(E) * 32 + r]

  // ---- load own-half theta (16 cols), stash to LDS ----
  float th[16];
  const float* sc = scores + node * 256 + e + p * 128;
#pragma unroll
  for (int c = 0; c < 16; ++c) th[c] = sc[c * 8];
#pragma unroll
  for (int c = 0; c < 16; ++c) L(16 * p + c) = th[c];

  // ---- up pass, subtree n4 = p only (exact OCML) ----
  float l1r[8], th2r[8];
#pragma unroll
  for (int n1l = 0; n1l < 8; ++n1l) {
    float tL = th[2 * n1l], tR = th[2 * n1l + 1];
    float amax = fmaxf(tR, tL);              // t0 = thR (j=0), t1 = thL
    float s = expf(tR - amax) + expf(tL - amax);
    l1r[n1l] = logf(s) + amax;
    th2r[n1l] = tL + tR;                      // exact: logf(1.0f)==0.0f
    int n1 = 8 * p + n1l;
    L(32 + n1) = l1r[n1l];
    L(48 + n1) = th2r[n1l];
  }
  float l2r[4][5];
#pragma unroll
  for (int n2l = 0; n2l < 4; ++n2l) {
    float aL[3] = {0.0f, l1r[2 * n2l], th2r[2 * n2l]};
    float aR[3] = {0.0f, l1r[2 * n2l + 1], th2r[2 * n2l + 1]};
    float o5[5];
    conv_level<3, 5, false>(aL, aR, o5);
    l2r[n2l][0] = 0.0f;
    int n2 = 4 * p + n2l;
#pragma unroll
    for (int m = 1; m < 5; ++m) { l2r[n2l][m] = o5[m]; L(64 + n2 * 4 + m - 1) = o5[m]; }
  }
  float l3r[2][9];
#pragma unroll
  for (int n3l = 0; n3l < 2; ++n3l) {
    float o9[9];
    conv_level<5, 9, false>(l2r[2 * n3l], l2r[2 * n3l + 1], o9);
    l3r[n3l][0] = 0.0f;
    int n3 = 2 * p + n3l;
#pragma unroll
    for (int m = 1; m < 9; ++m) { l3r[n3l][m] = o9[m]; L(96 + n3 * 8 + m - 1) = o9[m]; }
  }
  {
    float o9[9];
    conv_level<9, 9, false>(l3r[0], l3r[1], o9);
#pragma unroll
    for (int m = 1; m < 9; ++m) L(128 + p * 8 + m - 1) = o9[m];
  }

  // Pin ordering: all up-pass LDS writes precede all cross-half reads.
  __builtin_amdgcn_wave_barrier();

  // ---- read both L4 tables (cross-half; in-wave DS in-order) ----
  float A0[9], A1[9];
  A0[0] = 0.0f; A1[0] = 0.0f;
#pragma unroll
  for (int m = 1; m < 9; ++m) { A0[m] = L(128 + m - 1); A1[m] = L(136 + m - 1); }

  // ---- logZ (marginals only -> fast) ----
  float logZ;
  {
    float t[9];
#pragma unroll
    for (int j = 0; j < 9; ++j) t[j] = A0[j] + A1[8 - j];
    float amax = t[0];
#pragma unroll
    for (int j = 1; j < 9; ++j) amax = fmaxf(amax, t[j]);
    float s = 0.0f;
#pragma unroll
    for (int j = 0; j < 9; ++j) s += __expf(t[j] - amax);
    logZ = __logf(s) + amax;
  }

  // ---- down pass, subtrees n3 in {2p, 2p+1} (fast path) ----
  {
    float e4v[8];
    e4v[0] = 0.0f;
#pragma unroll
    for (int m = 1; m < 8; ++m) e4v[m] = p ? A0[m] : A1[m];  // sibling of n4=p
    float* mb = out + 2 * B * 32 + node * 256 + e;
#pragma unroll
    for (int n3l = 0; n3l < 2; ++n3l) {
      float e3[8];
      ext_level<9, 0, 7, true>(e4v, l3r[n3l ^ 1], e3);
#pragma unroll
      for (int c2 = 0; c2 < 2; ++c2) {
        const int n2l = 2 * n3l + c2;
        float e2v[8];
        ext_level<5, 4, 7, true>(e3, l2r[n2l ^ 1], e2v);
#pragma unroll
        for (int c1 = 0; c1 < 2; ++c1) {
          const int n1l = 2 * n2l + c1;
          float sib1[3] = {0.0f, l1r[n1l ^ 1], th2r[n1l ^ 1]};
          float e1m[8];
          ext_level<3, 6, 7, true>(e2v, sib1, e1m);
          const int colL = 16 * p + 2 * n1l;
          {
            float t6 = e1m[6] + th[2 * n1l + 1];
            float t7 = e1m[7];
            float amax = fmaxf(t6, t7);
            float s = __expf(t6 - amax) + __expf(t7 - amax);
            mb[colL * 8] = __expf((th[2 * n1l] + (__logf(s) + amax)) - logZ);
          }
          {
            float t6 = e1m[6] + th[2 * n1l];
            float t7 = e1m[7];
            float amax = fmaxf(t6, t7);
            float s = __expf(t6 - amax) + __expf(t7 - amax);
            mb[(colL + 1) * 8] = __expf((th[2 * n1l + 1] + (__logf(s) + amax)) - logZ);
          }
        }
      }
    }
  }

  // ---- top-down sampling, sample s = p (bit-exact path) ----
  const uint32_t t9 = (uint32_t)(p * B + row) * 9u;
  int c0, c1;
  {  // root, c = 8, static (A0/A1 regs)
    float best = 0.0f; int bj = 0;
#pragma unroll
    for (int j = 0; j < 9; ++j) {
      float g = gumbel_draw(keys.v[0], keys.v[1], t9 + (uint32_t)j);
      float v = (A0[j] + A1[8 - j]) + g;
      if (j == 0) { best = v; } else if (v > best) { best = v; bj = j; }
    }
    c0 = bj; c1 = 8 - bj;
  }
  int c1v[4];
  {  // li1: compacted flat loop, exactly (c0>0)(c0+1) + (c1>0)(c1+1) <= 10 draws
    const int n0 = c0 ? c0 + 1 : 0;
    const int n1c = c1 ? c1 + 1 : 0;
    const int tot = n0 + n1c;
    float b0 = -3.0e38f, b1 = -3.0e38f;
    int j0 = 0, j1 = 0;
    for (int t = 0; t < tot; ++t) {
      const bool is1 = (t >= n0);
      const int j = is1 ? (t - n0) : t;
      const int c = is1 ? c1 : c0;
      const int i = is1 ? 1 : 0;
      const int idx = c - j;                    // always in [0,8] (feasible)
      float aL = (j == 0) ? 0.0f : L(96 + 16 * i + j - 1);
      float aR = (idx == 0) ? 0.0f : L(96 + 16 * i + 8 + idx - 1);
      float g = gumbel_draw(keys.v[2], keys.v[3],
                            2u * t9 + (uint32_t)(9 * i + j));
      float v = (aL + aR) + g;
      if (is1) { if (v > b1) { b1 = v; j1 = j; } }
      else     { if (v > b0) { b0 = v; j0 = j; } }
    }
    c1v[0] = j0; c1v[1] = c0 - j0; c1v[2] = j1; c1v[3] = c1 - j1;
  }
  uint32_t pk2 = 0;
  {  // li2: 4 tasks, J=5, static (tables from LDS)
#pragma unroll
    for (int i = 0; i < 4; ++i) {
      int c = c1v[i];
      float best = -3.0e38f; int bj = 0;
#pragma unroll
      for (int j = 0; j < 5; ++j) {
        float g = gumbel_draw(keys.v[4], keys.v[5],
                              4u * t9 + (uint32_t)(i * 9 + j));
        int idx = c - j;
        int cl = min(max(idx, 1), 4);
        float ar = L(64 + (2 * i + 1) * 4 + cl - 1);
        float af = (idx == 0) ? 0.0f : ar;
        float aL = (j == 0) ? 0.0f : L(64 + (2 * i) * 4 + j - 1);
        float v = (aL + af) + g;
        if (idx >= 0 && idx <= 4 && v > best) { best = v; bj = j; }
      }
      pk2 |= ((uint32_t)bj << (8 * i)) | ((uint32_t)(c - bj) << (8 * i + 4));
    }
  }
  uint64_t pk64 = 0;
  {  // li3: 8 tasks, J=3, static (tables from LDS)
    const uint32_t sk0 = keys.v[6], sk1 = keys.v[7];
    const uint32_t fb0 = 8u * t9;
#pragma unroll 2
    for (int i = 0; i < 8; ++i) {
      int c = (int)((pk2 >> (4 * i)) & 15u);
      float aL1 = L(32 + 2 * i), aL2 = L(48 + 2 * i);
      float arm1 = L(32 + 2 * i + 1), arm2 = L(48 + 2 * i + 1);
      uint32_t fb = fb0 + (uint32_t)(i * 9);
      float best = -3.0e38f; int bj = 0;
#pragma unroll
      for (int j = 0; j < 3; ++j) {
        float g = gumbel_draw(sk0, sk1, fb + (uint32_t)j);
        int idx = c - j;
        float af = (idx == 1) ? arm1 : ((idx == 2) ? arm2 : 0.0f);
        float aLj = (j == 0) ? 0.0f : ((j == 1) ? aL1 : aL2);
        float v = (aLj + af) + g;
        if (idx >= 0 && idx <= 2 && v > best) { best = v; bj = j; }
      }
      pk64 |= ((uint64_t)(uint32_t)bj << (8 * i)) |
              ((uint64_t)(uint32_t)(c - bj) << (8 * i + 4));
    }
  }
  {  // li4: draws ONLY for c==1 leaf pairs (c=0 -> bj=0, c=2 -> bj=1, no draw)
    const uint32_t sk0 = keys.v[8], sk1 = keys.v[9];
    const uint32_t fb0 = 16u * t9;
    float* bs = out + p * (B * 32) + node * 256 + e;
    uint64_t lst = 0; int m4 = 0;
#pragma unroll
    for (int i = 0; i < 16; ++i) {
      int c = (int)((uint32_t)(pk64 >> (4 * i)) & 15u);
      if (c == 1) {
        lst |= ((uint64_t)(uint32_t)i) << (4 * m4);
        ++m4;
      } else {
        int bj = c >> 1;                        // 0->0, 2->1
        bs[16 * i] = (float)bj;
        bs[16 * i + 8] = (float)(c - bj);
      }
    }
    for (int t = 0; t < m4; ++t) {
      int i = (int)((lst >> (4 * t)) & 15u);
      float thL = L(2 * i);
      float thR = L(2 * i + 1);
      uint32_t fb = fb0 + (uint32_t)(i * 9);
      float g0 = gumbel_draw(sk0, sk1, fb);      // j=0: 0 + aR[1]=thR
      float g1 = gumbel_draw(sk0, sk1, fb + 1u); // j=1: thL + aR[0]=0
      float v0 = thR + g0;
      float v1 = thL + g1;
      int bj = (v1 > v0) ? 1 : 0;                // first-max: strict >
      bs[16 * i] = (float)bj;
      bs[16 * i + 8] = (float)(1 - bj);
    }
  }
#undef L
}

extern "C" void kernel_launch(void* const* d_in, const int* in_sizes, int n_in,
                              void* d_out, int out_size, void* d_ws, size_t ws_size,
                              hipStream_t stream) {
  const float* scores = (const float*)d_in[0];
  float* out = (float*)d_out;
  const int nnodes = in_sizes[0] / (32 * 8);   // 8192
  const int B = nnodes * 8;                    // 65536 rows

  // key = jax.random.key(42); per level: key, sub = split(key)
  // (partitionable threefry: new = tf(key,(0,0)), sub = tf(key,(0,1)))
  TFKeys K;
  uint32_t k0 = 0u, k1 = 42u;
  for (int t = 0; t < 5; ++t) {
    uint32_t n0, n1, s0, s1;
    tf2x32(k0, k1, 0u, 0u, n0, n1);
    tf2x32(k0, k1, 0u, 1u, s0, s1);
    K.v[2 * t] = s0; K.v[2 * t + 1] = s1;
    k0 = n0; k1 = n1;
  }

  dim3 grid((unsigned)(B / 64)), block(128);
  hipLaunchKernelGGL(simple_sampler_kernel, grid, block, 0, stream,
                     scores, out, nnodes, K);
}